// Round 18
// baseline (159.266 us; speedup 1.0000x reference)
//
#include <hip/hip_runtime.h>
#include <hip/hip_bf16.h>
#include <stdint.h>

#define MDIM 4096
#define NDIM 4096
#define KDIM 4096
#define NT 64   // K = 4096, BK = 64 — single bf16 pass (bf16-level harness tolerance)

typedef float f32x4 __attribute__((ext_vector_type(4)));
typedef short s16x8 __attribute__((ext_vector_type(8)));

__device__ __forceinline__ unsigned short f2bf(float x) {
  uint32_t u = __float_as_uint(x);
  uint32_t r = (u + 0x7fffu + ((u >> 16) & 1u)) >> 16;  // RNE
  return (unsigned short)r;
}

// ---------------- fused pre-pass: cast A -> bf16, cast+transpose B -> bf16 ----
__global__ __launch_bounds__(256) void split_fused(
    const float* __restrict__ A, const float* __restrict__ B,
    unsigned short* __restrict__ Ahi, unsigned short* __restrict__ BhiT) {
  __shared__ float tile[32][33];
  const int b = blockIdx.x;
  if (b < 16384) {
    size_t i = ((size_t)b * 256 + threadIdx.x) * 4;
    float4 v = *(const float4*)(A + i);
    ushort4 h;
    h.x = f2bf(v.x);
    h.y = f2bf(v.y);
    h.z = f2bf(v.z);
    h.w = f2bf(v.w);
    *(ushort4*)(Ahi + i) = h;
  } else {
    const int idx = b - 16384;
    const int n0 = (idx & 127) * 32;
    const int k0 = (idx >> 7) * 32;
    const int tx = threadIdx.x & 31;
    const int ty = threadIdx.x >> 5;  // 0..7
#pragma unroll
    for (int i = 0; i < 32; i += 8)
      tile[ty + i][tx] = B[(size_t)(k0 + ty + i) * NDIM + n0 + tx];
    __syncthreads();
#pragma unroll
    for (int i = 0; i < 32; i += 8) {
      size_t o = (size_t)(n0 + ty + i) * KDIM + k0 + tx;
      BhiT[o] = f2bf(tile[tx][ty + i]);
    }
  }
}

// ---------------- main GEMM: 256x256 tile, BK=64, 16 waves (4Mx4N), per-wave
// 64x64, 16x16x32 MFMA. Identical r15 4-phase vmcnt-FIFO schedule and LDS
// layout; waves/SIMD 2->4 so other waves' MFMA covers each phase's ds_read/
// stage issue window. 1 GLDS per unit per wave -> vmcnt(1) drains.
#define GLDS(gp, lp)                                              \
  __builtin_amdgcn_global_load_lds(                               \
      (const __attribute__((address_space(1))) void*)(gp),        \
      (__attribute__((address_space(3))) void*)(lp), 16, 0, 0)

#define BARRIER() asm volatile("s_barrier" ::: "memory")
#define WAITVM1() asm volatile("s_waitcnt vmcnt(1)" ::: "memory")
#define WAITVM2() asm volatile("s_waitcnt vmcnt(2)" ::: "memory")
#define WAITVM0() asm volatile("s_waitcnt vmcnt(0)" ::: "memory")

// stage one ks-half unit: ONE GLDS per wave (16 waves x 64 lanes x 16B = 16KB)
#define STAGE_U(rp, dst, ks)                                                     \
  GLDS((rp) + (ks) * 64, (dst) + (ks) * 16384 + dstBase)

#define RD_A4(dst, p)                                                            \
  _Pragma("unroll")                                                              \
  for (int m = 0; m < 4; ++m) dst[m] = *(const s16x8*)((p) + m * 1024)

#define MFMA8(AV, BV, NB)                                                        \
  __builtin_amdgcn_s_setprio(1);                                                 \
  _Pragma("unroll")                                                              \
  for (int m = 0; m < 4; ++m) {                                                  \
    acc[m][NB]     = __builtin_amdgcn_mfma_f32_16x16x32_bf16(AV[m], BV[0], acc[m][NB], 0, 0, 0);     \
    acc[m][NB + 1] = __builtin_amdgcn_mfma_f32_16x16x32_bf16(AV[m], BV[1], acc[m][NB + 1], 0, 0, 0); \
  }                                                                              \
  __builtin_amdgcn_s_setprio(0)

__global__ __launch_bounds__(1024, 4) void gemm_bf(
    const unsigned short* __restrict__ Ah, const unsigned short* __restrict__ BhT,
    float* __restrict__ C) {
  __shared__ __align__(16) char lds_[131072];  // 128 KiB ring-2

  const int tid = threadIdx.x;
  const int l   = tid & 63;
  const int wv  = tid >> 6;   // 0..15
  const int wm  = wv >> 2;    // 0..3
  const int wn  = wv & 3;     // 0..3
  const int fr  = l & 15;
  const int fq  = l >> 4;

  // bijective XCD swizzle (256 blocks)
  const int bid = blockIdx.x;
  const int swz = (bid & 7) * 32 + (bid >> 3);
  const int bm = swz >> 4, bn = swz & 15;

  // staging lane geometry (linear LDS dest; inverse-swizzled global src) [r6]
  const int lG     = (l & 7) ^ (l >> 3);
  const int g_radd = 2 * (l >> 3) + (lG >> 2);
  const int g_col  = (lG & 3) * 16;
  const int dstBase = wv * 1024;  // wave covers 16 matrix rows per unit

  // per-lane source offset (panel-relative, bytes)
  const size_t srcOff = (size_t)(wv * 16 + g_radd) * 8192 + g_col;

  // read lane geometry (swizzled ds_read; same involution, chunk-aligned) [r6]
  const int slot  = (((fr & 1) << 2) | fq) ^ ((fr >> 1) & 7);
  const int laneA = ((wm * 64 + fr) >> 1) * 128 + slot * 16;
  const int laneB = 65536 + ((wn * 64 + fr) >> 1) * 128 + slot * 16;

  const char* cAh = (const char*)Ah;
  const char* cBh = (const char*)BhT;
  const size_t aoff = (size_t)(bm * 256) * 8192 + srcOff;
  const size_t boff = (size_t)(bn * 256) * 8192 + srcOff;

  f32x4 acc[4][4] = {};
  s16x8 a0[4], a1[4], bX[2], bY[2];

  // ---- prologue: stage tile 0 (A0,B0,A1,B1); drain A0,B0 (vmcnt(2)) ----
  {
    const char* rA0 = cAh + aoff;
    const char* rB0 = cBh + boff;
    char* dA = lds_;
    char* dB = lds_ + 65536;
    STAGE_U(rA0, dA, 0);
    STAGE_U(rB0, dB, 0);
    STAGE_U(rA0, dA, 1);
    STAGE_U(rB0, dB, 1);
  }
  WAITVM2();   // A0,B0 resident; A1,B1 (2 loads) stay in flight
  BARRIER();
  RD_A4(a0, lds_ + laneA);
  bX[0] = *(const s16x8*)(lds_ + laneB);
  bX[1] = *(const s16x8*)(lds_ + laneB + 1024);

  const char* rpA = cAh + aoff + 128;   // src of tile t+1
  const char* rpB = cBh + boff + 128;
#pragma unroll 1
  for (int t = 0; t < NT - 1; ++t) {
    const int cb  = (t & 1) * 32768;
    const int cb2 = cb ^ 32768;
    char* dA = lds_ + cb2;            // buf of tile t+1
    char* dB = dA + 65536;
    const char* pa  = lds_ + cb + laneA;
    const char* pb  = lds_ + cb + laneB;
    const char* pa2 = lds_ + cb2 + laneA;
    const char* pb2 = lds_ + cb2 + laneB;

    // ---- ph0: read bY (n23, k0); stage A-ks0(t+1); MFMA (a0 x bX -> n01) ----
    bY[0] = *(const s16x8*)(pb + 2048);
    bY[1] = *(const s16x8*)(pb + 3072);
    STAGE_U(rpA, dA, 0);
    MFMA8(a0, bX, 0);

    // ---- ph1: drain ks1(t); read a1(k1) + bX(n01,k1); stage B-ks0(t+1); MFMA (a0 x bY -> n23)
    WAITVM1();
    BARRIER();
    RD_A4(a1, pa + 16384);
    bX[0] = *(const s16x8*)(pb + 16384);
    bX[1] = *(const s16x8*)(pb + 16384 + 1024);
    STAGE_U(rpB, dB, 0);
    MFMA8(a0, bY, 2);

    // ---- ph2: read bY (n23, k1); stage A-ks1(t+1); MFMA (a1 x bX -> n01) ----
    bY[0] = *(const s16x8*)(pb + 16384 + 2048);
    bY[1] = *(const s16x8*)(pb + 16384 + 3072);
    STAGE_U(rpA, dA, 1);
    MFMA8(a1, bX, 0);

    // ---- ph3: drain ks0(t+1); read t+1 k0 frags; stage B-ks1(t+1); MFMA (a1 x bY -> n23)
    WAITVM1();
    BARRIER();
    RD_A4(a0, pa2);
    bX[0] = *(const s16x8*)(pb2);
    bX[1] = *(const s16x8*)(pb2 + 1024);
    STAGE_U(rpB, dB, 1);
    MFMA8(a1, bY, 2);

    rpA += 128;
    rpB += 128;
  }

  // ---- peeled tail: t = NT-1 (no staging, no next-tile reads) ----
  {
    const int cb = ((NT - 1) & 1) * 32768;
    const char* pa = lds_ + cb + laneA;
    const char* pb = lds_ + cb + laneB;
    // ph0
    bY[0] = *(const s16x8*)(pb + 2048);
    bY[1] = *(const s16x8*)(pb + 3072);
    MFMA8(a0, bX, 0);
    // ph1 — drain this tile's ks1 units
    WAITVM0();
    BARRIER();
    RD_A4(a1, pa + 16384);
    bX[0] = *(const s16x8*)(pb + 16384);
    bX[1] = *(const s16x8*)(pb + 16384 + 1024);
    MFMA8(a0, bY, 2);
    // ph2
    bY[0] = *(const s16x8*)(pb + 16384 + 2048);
    bY[1] = *(const s16x8*)(pb + 16384 + 3072);
    MFMA8(a1, bX, 0);
    // ph3
    MFMA8(a1, bY, 2);
  }

  // ---- epilogue: C/D layout col=lane&15, row=(lane>>4)*4+j [verified] ----
  float* Cp = C + (size_t)(bm * 256 + wm * 64) * NDIM + (bn * 256 + wn * 64);
#pragma unroll
  for (int m = 0; m < 4; ++m)
#pragma unroll
    for (int n = 0; n < 4; ++n)
#pragma unroll
      for (int j = 0; j < 4; ++j)
        Cp[(size_t)(m * 16 + fq * 4 + j) * NDIM + n * 16 + fr] = acc[m][n][j];
}

// ---------------- fallback: plain fp32 tiled GEMM (ws too small) ----------------
__global__ __launch_bounds__(1024) void gemm_fp32_fallback(const float* __restrict__ A,
                                                           const float* __restrict__ B,
                                                           float* __restrict__ C) {
  __shared__ float As[32][33];
  __shared__ float Bs[32][33];
  int tx = threadIdx.x, ty = threadIdx.y;
  int row = blockIdx.y * 32 + ty, colg = blockIdx.x * 32 + tx;
  float acc = 0.f;
  for (int k0 = 0; k0 < KDIM; k0 += 32) {
    As[ty][tx] = A[(size_t)row * KDIM + k0 + tx];
    Bs[ty][tx] = B[(size_t)(k0 + ty) * NDIM + colg];
    __syncthreads();
#pragma unroll 8
    for (int kk = 0; kk < 32; ++kk) acc += As[ty][kk] * Bs[kk][tx];
    __syncthreads();
  }
  C[(size_t)row * NDIM + colg] = acc;
}

extern "C" void kernel_launch(void* const* d_in, const int* in_sizes, int n_in,
                              void* d_out, int out_size, void* d_ws, size_t ws_size,
                              hipStream_t stream) {
  const float* A = (const float*)d_in[0];
  const float* B = (const float*)d_in[1];
  float* C = (float*)d_out;

  const size_t elems = (size_t)MDIM * KDIM;
  const size_t need = 2 * elems * sizeof(unsigned short);  // 64 MB
  if (ws_size < need) {
    gemm_fp32_fallback<<<dim3(NDIM / 32, MDIM / 32), dim3(32, 32), 0, stream>>>(A, B, C);
    return;
  }

  unsigned short* Ah  = (unsigned short*)d_ws;
  unsigned short* BhT = Ah + elems;

  split_fused<<<dim3(16384 + 16384), dim3(256), 0, stream>>>(A, B, Ah, BhT);
  gemm_bf<<<dim3(256), dim3(1024), 0, stream>>>(Ah, BhT, C);
}

// Round 19
// 145.301 us; speedup vs baseline: 1.0961x; 1.0961x over previous
//
#include <hip/hip_runtime.h>
#include <hip/hip_bf16.h>
#include <stdint.h>

#define MDIM 4096
#define NDIM 4096
#define KDIM 4096
#define NT 64   // K = 4096, BK = 64 — single bf16 pass (bf16-level harness tolerance)

typedef float f32x4 __attribute__((ext_vector_type(4)));
typedef short s16x8 __attribute__((ext_vector_type(8)));

__device__ __forceinline__ unsigned short f2bf(float x) {
  uint32_t u = __float_as_uint(x);
  uint32_t r = (u + 0x7fffu + ((u >> 16) & 1u)) >> 16;  // RNE
  return (unsigned short)r;
}

// ---------------- fused pre-pass: cast A -> bf16, cast+transpose B -> bf16 ----
__global__ __launch_bounds__(256) void split_fused(
    const float* __restrict__ A, const float* __restrict__ B,
    unsigned short* __restrict__ Ahi, unsigned short* __restrict__ BhiT) {
  __shared__ float tile[32][33];
  const int b = blockIdx.x;
  if (b < 16384) {
    size_t i = ((size_t)b * 256 + threadIdx.x) * 4;
    float4 v = *(const float4*)(A + i);
    ushort4 h;
    h.x = f2bf(v.x);
    h.y = f2bf(v.y);
    h.z = f2bf(v.z);
    h.w = f2bf(v.w);
    *(ushort4*)(Ahi + i) = h;
  } else {
    const int idx = b - 16384;
    const int n0 = (idx & 127) * 32;
    const int k0 = (idx >> 7) * 32;
    const int tx = threadIdx.x & 31;
    const int ty = threadIdx.x >> 5;  // 0..7
#pragma unroll
    for (int i = 0; i < 32; i += 8)
      tile[ty + i][tx] = B[(size_t)(k0 + ty + i) * NDIM + n0 + tx];
    __syncthreads();
#pragma unroll
    for (int i = 0; i < 32; i += 8) {
      size_t o = (size_t)(n0 + ty + i) * KDIM + k0 + tx;
      BhiT[o] = f2bf(tile[tx][ty + i]);
    }
  }
}

// ---------------- main GEMM: 256x256, BK=64, 8 waves (2Mx4N), per-wave 128x64,
// 16x16x32 MFMA. r6/r15 register-fragment pipeline (measured best: 114.5us,
// 0 bank conflicts, MfmaUtil 54%), single K-segment, counted vmcnt FIFO.
#define GLDS(gp, lp)                                              \
  __builtin_amdgcn_global_load_lds(                               \
      (const __attribute__((address_space(1))) void*)(gp),        \
      (__attribute__((address_space(3))) void*)(lp), 16, 0, 0)

#define BARRIER() asm volatile("s_barrier" ::: "memory")
#define WAITVM2() asm volatile("s_waitcnt vmcnt(2)" ::: "memory")
#define WAITVM4() asm volatile("s_waitcnt vmcnt(4)" ::: "memory")
#define WAITVM0() asm volatile("s_waitcnt vmcnt(0)" ::: "memory")

// stage one ks-half unit (2 GLDS) from running src ptr rp into tile dst
#define STAGE_U(rp, dst, ks)                                                     \
  GLDS((rp) + (ks) * 64,          (dst) + (ks) * 16384 + dstBase);               \
  GLDS((rp) + 131072 + (ks) * 64, (dst) + (ks) * 16384 + dstBase + 1024)

#define RD_A4(dst, p)                                                            \
  _Pragma("unroll")                                                              \
  for (int m = 0; m < 4; ++m) dst[m] = *(const s16x8*)((p) + m * 1024)
#define RD_B4(dst, p)                                                            \
  _Pragma("unroll")                                                              \
  for (int n = 0; n < 4; ++n) dst[n] = *(const s16x8*)((p) + n * 1024)

#define MFMA_CL(MB, AV, BV)                                                      \
  __builtin_amdgcn_s_setprio(1);                                                 \
  _Pragma("unroll")                                                              \
  for (int m = 0; m < 4; ++m) {                                                  \
    _Pragma("unroll")                                                            \
    for (int n = 0; n < 4; ++n)                                                  \
      acc[MB + m][n] =                                                           \
          __builtin_amdgcn_mfma_f32_16x16x32_bf16(AV[m], BV[n], acc[MB + m][n], 0, 0, 0); \
  }                                                                              \
  __builtin_amdgcn_s_setprio(0)

__global__ __launch_bounds__(512, 2) void gemm_bf(
    const unsigned short* __restrict__ Ah, const unsigned short* __restrict__ BhT,
    float* __restrict__ C) {
  __shared__ __align__(16) char lds_[131072];  // 128 KiB ring-2

  const int tid = threadIdx.x;
  const int l   = tid & 63;
  const int wv  = tid >> 6;   // 0..7
  const int wm  = wv >> 2;    // 0..1
  const int wn  = wv & 3;     // 0..3
  const int fr  = l & 15;
  const int fq  = l >> 4;

  // bijective XCD swizzle (256 blocks)
  const int bid = blockIdx.x;
  const int swz = (bid & 7) * 32 + (bid >> 3);
  const int bm = swz >> 4, bn = swz & 15;

  // staging lane geometry (linear LDS dest; inverse-swizzled global src) [r6]
  const int lG     = (l & 7) ^ (l >> 3);
  const int g_radd = 2 * (l >> 3) + (lG >> 2);
  const int g_col  = (lG & 3) * 16;
  const int dstBase = wv * 2048;  // (wv*32 rows) * 64 B

  // per-lane source offset (panel-relative, bytes)
  const size_t srcOff = (size_t)(wv * 32 + g_radd) * 8192 + g_col;

  // read lane geometry (swizzled ds_read; same involution) [r6]
  const int slot  = (((fr & 1) << 2) | fq) ^ ((fr >> 1) & 7);
  const int laneA = ((wm * 128 + fr) >> 1) * 128 + slot * 16;
  const int laneB = 65536 + ((wn * 64 + fr) >> 1) * 128 + slot * 16;

  const char* cAh = (const char*)Ah;
  const char* cBh = (const char*)BhT;
  const size_t aoff = (size_t)(bm * 256) * 8192 + srcOff;
  const size_t boff = (size_t)(bn * 256) * 8192 + srcOff;

  f32x4 acc[8][4] = {};
  s16x8 aX[4], aY[4], b0[4], b1[4];

  // ---- prologue: stage tile 0 (A0,B0,A1,B1); drain only A0,B0 (vmcnt(4)) ----
  {
    const char* rA0 = cAh + aoff;
    const char* rB0 = cBh + boff;
    char* dA = lds_;
    char* dB = lds_ + 65536;
    STAGE_U(rA0, dA, 0);
    STAGE_U(rB0, dB, 0);
    STAGE_U(rA0, dA, 1);
    STAGE_U(rB0, dB, 1);
  }
  WAITVM4();   // A0,B0 resident; A1,B1 (4 loads) stay in flight
  BARRIER();
  RD_A4(aX, lds_ + laneA);
  RD_B4(b0, lds_ + laneB);

  const char* rpA = cAh + aoff + 128;   // src of tile t+1
  const char* rpB = cBh + boff + 128;
#pragma unroll 1
  for (int t = 0; t < NT - 1; ++t) {
    const int cb  = (t & 1) * 32768;
    const int cb2 = cb ^ 32768;
    char* dA = lds_ + cb2;            // buf of tile t+1
    char* dB = dA + 65536;
    const char* pa  = lds_ + cb + laneA;
    const char* pb  = lds_ + cb + laneB;
    const char* pa2 = lds_ + cb2 + laneA;
    const char* pb2 = lds_ + cb2 + laneB;

    // ---- ph0: read c1 frags (m4-7, k0); stage A-ks0(t+1); MFMA c0 ----
    RD_A4(aY, pa + 4096);
    STAGE_U(rpA, dA, 0);
    MFMA_CL(0, aX, b0);

    // ---- ph1: drain ks1(t); read (m0-3,k1)+b(k1); stage B-ks0(t+1); MFMA c1
    WAITVM2();
    BARRIER();
    RD_A4(aX, pa + 16384);
    RD_B4(b1, pb + 16384);
    STAGE_U(rpB, dB, 0);
    MFMA_CL(4, aY, b0);

    // ---- ph2: read c3 frags (m4-7, k1); stage A-ks1(t+1); MFMA c2 ----
    RD_A4(aY, pa + 16384 + 4096);
    STAGE_U(rpA, dA, 1);
    MFMA_CL(0, aX, b1);

    // ---- ph3: drain ks0(t+1); read t+1 c0 frags; stage B-ks1(t+1); MFMA c3
    WAITVM2();
    BARRIER();
    RD_A4(aX, pa2);
    RD_B4(b0, pb2);
    STAGE_U(rpB, dB, 1);
    MFMA_CL(4, aY, b1);

    rpA += 128;
    rpB += 128;
  }

  // ---- peeled tail: t = NT-1 (no staging, no next-tile reads) ----
  {
    const int cb = ((NT - 1) & 1) * 32768;
    const char* pa = lds_ + cb + laneA;
    const char* pb = lds_ + cb + laneB;
    // ph0
    RD_A4(aY, pa + 4096);
    MFMA_CL(0, aX, b0);
    // ph1 — drain this tile's ks1 units
    WAITVM0();
    BARRIER();
    RD_A4(aX, pa + 16384);
    RD_B4(b1, pb + 16384);
    MFMA_CL(4, aY, b0);
    // ph2
    RD_A4(aY, pa + 16384 + 4096);
    MFMA_CL(0, aX, b1);
    // ph3
    MFMA_CL(4, aY, b1);
  }

  // ---- epilogue: C/D layout col=lane&15, row=(lane>>4)*4+j [verified] ----
  float* Cp = C + (size_t)(bm * 256 + wm * 128) * NDIM + (bn * 256 + wn * 64);
#pragma unroll
  for (int m = 0; m < 8; ++m)
#pragma unroll
    for (int n = 0; n < 4; ++n)
#pragma unroll
      for (int j = 0; j < 4; ++j)
        Cp[(size_t)(m * 16 + fq * 4 + j) * NDIM + n * 16 + fr] = acc[m][n][j];
}

// ---------------- fallback: plain fp32 tiled GEMM (ws too small) ----------------
__global__ __launch_bounds__(1024) void gemm_fp32_fallback(const float* __restrict__ A,
                                                           const float* __restrict__ B,
                                                           float* __restrict__ C) {
  __shared__ float As[32][33];
  __shared__ float Bs[32][33];
  int tx = threadIdx.x, ty = threadIdx.y;
  int row = blockIdx.y * 32 + ty, colg = blockIdx.x * 32 + tx;
  float acc = 0.f;
  for (int k0 = 0; k0 < KDIM; k0 += 32) {
    As[ty][tx] = A[(size_t)row * KDIM + k0 + tx];
    Bs[ty][tx] = B[(size_t)(k0 + ty) * NDIM + colg];
    __syncthreads();
#pragma unroll 8
    for (int kk = 0; kk < 32; ++kk) acc += As[ty][kk] * Bs[kk][tx];
    __syncthreads();
  }
  C[(size_t)row * NDIM + colg] = acc;
}

extern "C" void kernel_launch(void* const* d_in, const int* in_sizes, int n_in,
                              void* d_out, int out_size, void* d_ws, size_t ws_size,
                              hipStream_t stream) {
  const float* A = (const float*)d_in[0];
  const float* B = (const float*)d_in[1];
  float* C = (float*)d_out;

  const size_t elems = (size_t)MDIM * KDIM;
  const size_t need = 2 * elems * sizeof(unsigned short);  // 64 MB
  if (ws_size < need) {
    gemm_fp32_fallback<<<dim3(NDIM / 32, MDIM / 32), dim3(32, 32), 0, stream>>>(A, B, C);
    return;
  }

  unsigned short* Ah  = (unsigned short*)d_ws;
  unsigned short* BhT = Ah + elems;

  split_fused<<<dim3(16384 + 16384), dim3(256), 0, stream>>>(A, B, Ah, BhT);
  gemm_bf<<<dim3(256), dim3(512), 0, stream>>>(Ah, BhT, C);
}